// Round 3
// baseline (295.860 us; speedup 1.0000x reference)
//
#include <hip/hip_runtime.h>
#include <hip/hip_bf16.h>
#include <cstdint>
#include <cstddef>

// B=4, S=2048, D=1024. Inputs fp32 (runtime-detected per-kernel, bf16 path kept).
// Round-10 GEMM: 256x128 block tile, 8 waves (4M x 2N), per-wave 64x64
// (2x2 32x32x16 bf16 MFMAs, acc=64 regs). K64 slabs, [row][64 u16] LDS with
// 8-slot XOR swizzle (slot = g ^ (row&7)), staged pre-swizzled via linear
// global_load_lds. Ring-3 slabs + counted vmcnt(6): one slab always in
// flight across the barrier (T4). ONE barrier per K64 iter; fragment reads
// pipelined one k-step ahead of the MFMA consuming them, so LDS reads
// overlap MFMA within each wave (m201 mechanism).
//   iter j: read ks0,ks1 ; stage(j+2 -> slot (j+2)%3) ; MFMA ks0 ; read ks2 ;
//           MFMA ks1 ; read ks3 ; MFMA ks2,ks3 ; vmcnt(6) ; barrier
// Hazards: slot (j+2)%3 == slot (j-1)%3 whose reads retired before the
// j-1 end barrier (lgkm waits precede consuming MFMAs). vmcnt(6) at iter end
// certifies slab j+1 (its 6 loads are the oldest outstanding), keeps slab
// j+2's 6 loads in flight.
// Tile counts divide 256 CUs exactly (1 block/CU, 144 KB LDS):
//   QKV 24x32 = 768 (3 rounds), QK 16x8x4 = 512 (2), PV 8x8x4 = 256 (1).
//
// d_ws layout (16B-aligned, ~118 MB):
//   bias5 @ 16           10,240   (bq|bk|bv|gamma|beta bf16)
//   Wt    @ 16,384       6,291,456
//   QKV   @ 6,307,840    50,331,648
//   Xb    @ 56,639,488   16,777,216
//   S4/P4 @ 73,416,704   33,554,432
//   Vt4   @ 106,971,136  16,777,216   (end 123,748,352)

typedef unsigned short u16;
using bf16x8 = __attribute__((ext_vector_type(8))) short;
using f32x16 = __attribute__((ext_vector_type(16))) float;

typedef __attribute__((address_space(3))) unsigned int lds_uint;
typedef const __attribute__((address_space(1))) unsigned int glob_uint;

__device__ __forceinline__ float bf2f(u16 h) {
    union { unsigned int u; float f; } c;
    c.u = ((unsigned int)h) << 16;
    return c.f;
}
__device__ __forceinline__ u16 f2bf(float f) {
    union { float f; unsigned int u; } c;
    c.f = f;
    return (u16)((c.u + 0x7fffu + ((c.u >> 16) & 1u)) >> 16);  // RNE
}
__device__ __forceinline__ void load_lds16(const void* g, void* l) {
    __builtin_amdgcn_global_load_lds((glob_uint*)g, (lds_uint*)l, 16, 0, 0);
}

// Inline dtype detection: even-index u16s of X decode as bf16 to small finite
// nonzero values iff X is bf16; fp32 mantissa halves produce huge/NaN decodes.
__device__ __forceinline__ int detect_fp32(const u16* X, int* sflag) {
    const int t = threadIdx.x;
    if (t < 64) {
        bool bad = false, nz = false;
#pragma unroll
        for (int j = 0; j < 4; ++j) {
            float v = bf2f(X[(t * 4 + j) * 2]);
            if (!(fabsf(v) <= 1e9f)) bad = true;
            if (v != 0.f) nz = true;
        }
        unsigned long long ab = __ballot(bad);
        unsigned long long an = __ballot(nz);
        if (t == 0) *sflag = (ab != 0ull || an == 0ull) ? 1 : 0;
    }
    __syncthreads();
    return *sflag;
}

// ------------------------------------------------------------------- prep
__global__ __launch_bounds__(256) void prep_kernel(
    const void* __restrict__ X, const void* __restrict__ Wq,
    const void* __restrict__ Wk, const void* __restrict__ Wv,
    const void* __restrict__ bq, const void* __restrict__ bk,
    const void* __restrict__ bv, const void* __restrict__ gamma,
    const void* __restrict__ beta,
    u16* __restrict__ Xb, u16* __restrict__ Wt, u16* __restrict__ bias5)
{
    __shared__ u16 tile[64][72];
    __shared__ int sflag;
    const int fp32 = detect_fp32((const u16*)X, &sflag);
    const int t   = threadIdx.x;
    const int blk = blockIdx.x;

    if (blk < 4096) {                       // ---- convert X
        const size_t i = ((size_t)blk * 256 + t) * 8;
        if (fp32) {
            const float* f = (const float*)X;
            float4 a = *(const float4*)(f + i);
            float4 b = *(const float4*)(f + i + 4);
            ushort4 o0, o1;
            o0.x = f2bf(a.x); o0.y = f2bf(a.y); o0.z = f2bf(a.z); o0.w = f2bf(a.w);
            o1.x = f2bf(b.x); o1.y = f2bf(b.y); o1.z = f2bf(b.z); o1.w = f2bf(b.w);
            *(ushort4*)(Xb + i) = o0;
            *(ushort4*)(Xb + i + 4) = o1;
        } else {
            *(uint4*)(Xb + i) = *(const uint4*)((const u16*)X + i);
        }
    } else if (blk < 4864) {                // ---- transpose W
        const int idx = blk - 4096;
        const int k0 = (idx & 15) * 64;
        const int n0 = ((idx >> 4) & 15) * 64;
        const int w  = idx >> 8;
        const void* W = (w == 0) ? Wq : ((w == 1) ? Wk : Wv);
#pragma unroll
        for (int it = 0; it < 2; ++it) {
            int i2 = t + it * 256;
            int r = i2 >> 3;
            int c = (i2 & 7) * 8;
            const size_t off = (size_t)(k0 + r) * 1024 + n0 + c;
            if (fp32) {
                const float* Wf = (const float*)W + off;
                float4 a = *(const float4*)Wf;
                float4 b = *(const float4*)(Wf + 4);
                u16* tp = &tile[r][c];
                tp[0] = f2bf(a.x); tp[1] = f2bf(a.y); tp[2] = f2bf(a.z); tp[3] = f2bf(a.w);
                tp[4] = f2bf(b.x); tp[5] = f2bf(b.y); tp[6] = f2bf(b.z); tp[7] = f2bf(b.w);
            } else {
                *(uint4*)&tile[r][c] = *(const uint4*)((const u16*)W + off);
            }
        }
        __syncthreads();
#pragma unroll
        for (int it = 0; it < 2; ++it) {
            int i2 = t + it * 256;
            int r = i2 >> 3;
            int c = (i2 & 7) * 8;
            union { u16 s[8]; uint4 v; } tmp;
#pragma unroll
            for (int j = 0; j < 8; ++j) tmp.s[j] = tile[c + j][r];
            *(uint4*)(Wt + (size_t)(w * 1024 + n0 + r) * 1024 + k0 + c) = tmp.v;
        }
    } else {                                // ---- small vectors
        const int v = blk - 4864;
        const void* srcs[5] = {bq, bk, bv, gamma, beta};
        const void* src = srcs[v];
        u16* d = bias5 + (size_t)v * 1024;
        const int i = t * 4;
        if (fp32) {
            const float* f = (const float*)src;
            ushort4 o;
            o.x = f2bf(f[i]); o.y = f2bf(f[i + 1]);
            o.z = f2bf(f[i + 2]); o.w = f2bf(f[i + 3]);
            *(ushort4*)(d + i) = o;
        } else {
            *(ushort4*)(d + i) = *(const ushort4*)((const u16*)src + i);
        }
    }
}

// ------------------------------------------------------------ transpose V (4)
__global__ __launch_bounds__(256) void transpose_v4_kernel(
    const u16* __restrict__ QKV, u16* __restrict__ Vt4)
{
    __shared__ u16 tile[64][72];
    const int t  = threadIdx.x;
    const int k0 = blockIdx.x * 64;     // s
    const int n0 = blockIdx.y * 64;     // d
    const int b  = blockIdx.z;
    const u16* Vsrc = QKV + (size_t)b * 2048 * 3072 + 2048;
    u16* Vt = Vt4 + (size_t)b * 1024 * 2048;
#pragma unroll
    for (int it = 0; it < 2; ++it) {
        int idx = t + it * 256;
        int r = idx >> 3;
        int c = (idx & 7) * 8;
        *(uint4*)&tile[r][c] = *(const uint4*)(Vsrc + (size_t)(k0 + r) * 3072 + n0 + c);
    }
    __syncthreads();
#pragma unroll
    for (int it = 0; it < 2; ++it) {
        int idx = t + it * 256;
        int r = idx >> 3;
        int c = (idx & 7) * 8;
        union { u16 s[8]; uint4 v; } tmp;
#pragma unroll
        for (int j = 0; j < 8; ++j) tmp.s[j] = tile[c + j][r];
        *(uint4*)(Vt + (size_t)(n0 + r) * 2048 + k0 + c) = tmp.v;
    }
}

// ------------------------------------ GEMM 256x128, K64 ring-3, 1 barrier
// LDS element map: LDS[sl][row][slot*8+e] = G[row][64*slab + (slot^(row&7))*8 + e]
// Stage (linear dest): round i, thread t writes LDS 16B-unit i*512+t ->
//   row = i*64 + (t>>3), phys slot = t&7, global k-group g = (t&7) ^ ((t>>3)&7).
// Read: frag row = wm*64 + mi*32 + lr (lr = l&31), k-step ks needs
//   g = 2*ks + kh (kh = l>>5); phys slot = g ^ (lr&7).
// C/D layout (m74/m101): col = lane&31, row = (r&3) + 8*(r>>2) + 4*(lane>>5).
#define MFMA4(A0, A1, B0, B1)                                                   \
    __builtin_amdgcn_s_setprio(1);                                              \
    acc[0][0] = __builtin_amdgcn_mfma_f32_32x32x16_bf16(A0, B0, acc[0][0], 0, 0, 0); \
    acc[0][1] = __builtin_amdgcn_mfma_f32_32x32x16_bf16(A0, B1, acc[0][1], 0, 0, 0); \
    acc[1][0] = __builtin_amdgcn_mfma_f32_32x32x16_bf16(A1, B0, acc[1][0], 0, 0, 0); \
    acc[1][1] = __builtin_amdgcn_mfma_f32_32x32x16_bf16(A1, B1, acc[1][1], 0, 0, 0); \
    __builtin_amdgcn_s_setprio(0);

template<int EPI>
__global__ __launch_bounds__(512, 2) void gemm256x128(
    const u16* __restrict__ A, int lda, size_t sA,
    const u16* __restrict__ Bt, int ldb, size_t sB,
    u16* __restrict__ C, int ldc, size_t sC,
    int K, float scale, const u16* __restrict__ bias3)
{
    __shared__ u16 As[3][256 * 64];     // 3 x 32 KB
    __shared__ u16 Bs[3][128 * 64];     // 3 x 16 KB  (total 144 KB)

    const int t  = threadIdx.x;
    const int l  = t & 63;
    const int w  = t >> 6;              // 0..7
    const int wm = w >> 1;              // 0..3
    const int wn = w & 1;               // 0..1
    const int m0 = blockIdx.y * 256;
    const int n0 = blockIdx.x * 128;
    A  += (size_t)blockIdx.z * sA;
    Bt += (size_t)blockIdx.z * sB;
    C  += (size_t)blockIdx.z * sC;

    // ---- staging constants (pre-swizzled global source, linear LDS dest)
    const int srow = t >> 3;                        // row within 64-row round
    const int sg   = (t & 7) ^ ((t >> 3) & 7);      // global k-group for lane
    const u16* Ag = A  + (size_t)(m0 + srow) * lda + sg * 8;
    const u16* Bg = Bt + (size_t)(n0 + srow) * ldb + sg * 8;

    auto stage = [&](int j, int sl) {
        const size_t kb = (size_t)j * 64;
        const u16* ag = Ag + kb;
        const u16* bg = Bg + kb;
        u16* al = &As[sl][w * 512];
        u16* bl = &Bs[sl][w * 512];
#pragma unroll
        for (int i = 0; i < 4; ++i)
            load_lds16(ag + (size_t)i * 64 * lda, al + i * 4096);
#pragma unroll
        for (int i = 0; i < 2; ++i)
            load_lds16(bg + (size_t)i * 64 * ldb, bl + i * 4096);
    };

    // ---- read-side constants
    const int lr   = l & 31;
    const int kh   = l >> 5;            // 0..1
    const int keyr = lr & 7;
    const int aoff = (wm * 64 + lr) * 64;
    const int boff = (wn * 64 + lr) * 64;

    f32x16 acc[2][2];
#pragma unroll
    for (int mi = 0; mi < 2; ++mi)
#pragma unroll
        for (int ni = 0; ni < 2; ++ni)
#pragma unroll
            for (int r = 0; r < 16; ++r) acc[mi][ni][r] = 0.f;

    const int NS = K >> 6;              // K64 slabs (>= 16 for all our shapes)

    // prologue: slabs 0,1 in flight; certify 0 (slab 1's 6 loads stay out)
    stage(0, 0);
    stage(1, 1);
    asm volatile("s_waitcnt vmcnt(6)" ::: "memory");
    __builtin_amdgcn_s_barrier();
    asm volatile("" ::: "memory");

    int sl = 0;
    for (int j = 0; j < NS; ++j) {
        const u16* as_ = &As[sl][aoff];
        const u16* bs_ = &Bs[sl][boff];
        bf16x8 aE0, aE1, bE0, bE1, aO0, aO1, bO0, bO1;
        // k-steps 0 (E) and 1 (O) read up-front
        {
            const int sp = (kh ^ keyr) * 8;
            aE0 = *(const bf16x8*)(as_ + sp);
            aE1 = *(const bf16x8*)(as_ + 2048 + sp);
            bE0 = *(const bf16x8*)(bs_ + sp);
            bE1 = *(const bf16x8*)(bs_ + 2048 + sp);
        }
        {
            const int sp = ((2 + kh) ^ keyr) * 8;
            aO0 = *(const bf16x8*)(as_ + sp);
            aO1 = *(const bf16x8*)(as_ + 2048 + sp);
            bO0 = *(const bf16x8*)(bs_ + sp);
            bO1 = *(const bf16x8*)(bs_ + 2048 + sp);
        }
        // prefetch slab j+2 into slot (j+2)%3 (readers retired at j-1's barrier)
        if (j + 2 < NS) {
            int s2 = sl + 2; if (s2 >= 3) s2 -= 3;
            stage(j + 2, s2);
        }
        MFMA4(aE0, aE1, bE0, bE1);                      // k-step 0
        {
            const int sp = ((4 + kh) ^ keyr) * 8;       // k-step 2 -> E regs
            aE0 = *(const bf16x8*)(as_ + sp);
            aE1 = *(const bf16x8*)(as_ + 2048 + sp);
            bE0 = *(const bf16x8*)(bs_ + sp);
            bE1 = *(const bf16x8*)(bs_ + 2048 + sp);
        }
        MFMA4(aO0, aO1, bO0, bO1);                      // k-step 1
        {
            const int sp = ((6 + kh) ^ keyr) * 8;       // k-step 3 -> O regs
            aO0 = *(const bf16x8*)(as_ + sp);
            aO1 = *(const bf16x8*)(as_ + 2048 + sp);
            bO0 = *(const bf16x8*)(bs_ + sp);
            bO1 = *(const bf16x8*)(bs_ + 2048 + sp);
        }
        MFMA4(aE0, aE1, bE0, bE1);                      // k-step 2
        MFMA4(aO0, aO1, bO0, bO1);                      // k-step 3
        if (j + 1 < NS) {
            if (j + 2 < NS) {
                // certify slab j+1 (oldest 6 outstanding); keep j+2 in flight
                asm volatile("s_waitcnt vmcnt(6)" ::: "memory");
            } else {
                asm volatile("s_waitcnt vmcnt(0)" ::: "memory");
            }
            __builtin_amdgcn_s_barrier();
            asm volatile("" ::: "memory");
        }
        sl = (sl == 2) ? 0 : sl + 1;
    }

    // epilogue: C/D layout (m74/m101)
    const int colb = n0 + wn * 64 + lr;
    const int rowb = m0 + wm * 64 + 4 * kh;
#pragma unroll
    for (int mi = 0; mi < 2; ++mi) {
#pragma unroll
        for (int ni = 0; ni < 2; ++ni) {
            const int col = colb + ni * 32;
            const float bias = (EPI == 0) ? bf2f(bias3[col]) : 0.f;
#pragma unroll
            for (int r = 0; r < 16; ++r) {
                const int row = rowb + mi * 32 + (r & 3) + 8 * (r >> 2);
                C[(size_t)row * ldc + col] = f2bf(acc[mi][ni][r] * scale + bias);
            }
        }
    }
}

// ----------------------------------------------------------- softmax (bf16)
__global__ __launch_bounds__(256) void softmax_bf16_kernel(u16* __restrict__ S)
{
    const int t = threadIdx.x;
    u16* sp = S + (size_t)blockIdx.x * 2048;
    union { uint4 v; u16 h[8]; } raw;
    raw.v = *(const uint4*)(sp + t * 8);
    float vals[8];
#pragma unroll
    for (int i = 0; i < 8; ++i) vals[i] = bf2f(raw.h[i]);
    float m = vals[0];
#pragma unroll
    for (int i = 1; i < 8; ++i) m = fmaxf(m, vals[i]);
#pragma unroll
    for (int off = 32; off > 0; off >>= 1) m = fmaxf(m, __shfl_xor(m, off));
    __shared__ float red[8];
    const int w = t >> 6, lane = t & 63;
    if (lane == 0) red[w] = m;
    __syncthreads();
    m = fmaxf(fmaxf(red[0], red[1]), fmaxf(red[2], red[3]));
    float e[8], s = 0.f;
#pragma unroll
    for (int i = 0; i < 8; ++i) { e[i] = __expf(vals[i] - m); s += e[i]; }
#pragma unroll
    for (int off = 32; off > 0; off >>= 1) s += __shfl_xor(s, off);
    if (lane == 0) red[4 + w] = s;
    __syncthreads();
    s = red[4] + red[5] + red[6] + red[7];
    const float rinv = 1.f / s;
    union { uint4 v; u16 h[8]; } out;
#pragma unroll
    for (int i = 0; i < 8; ++i) out.h[i] = f2bf(e[i] * rinv);
    *(uint4*)(sp + t * 8) = out.v;
}

// ---------------------------------------------------------------- resid + LN
__global__ __launch_bounds__(256) void resid_ln_kernel(
    const u16* __restrict__ Ctx, const u16* __restrict__ Xb,
    const u16* __restrict__ gamma, const u16* __restrict__ beta,
    void* __restrict__ Out, const u16* __restrict__ Xraw)
{
    __shared__ int sflag;
    const int fp32 = detect_fp32(Xraw, &sflag);
    const size_t row = blockIdx.x;
    const int t = threadIdx.x;
    ushort4 cv = *(const ushort4*)(Ctx + row * 3072 + t * 4);
    ushort4 xv = *(const ushort4*)(Xb + row * 1024 + t * 4);
    float v[4] = {bf2f(cv.x) + bf2f(xv.x), bf2f(cv.y) + bf2f(xv.y),
                  bf2f(cv.z) + bf2f(xv.z), bf2f(cv.w) + bf2f(xv.w)};
    float s  = v[0] + v[1] + v[2] + v[3];
    float s2 = v[0] * v[0] + v[1] * v[1] + v[2] * v[2] + v[3] * v[3];
#pragma unroll
    for (int off = 32; off > 0; off >>= 1) {
        s  += __shfl_xor(s, off);
        s2 += __shfl_xor(s2, off);
    }
    __shared__ float red[8];
    const int w = t >> 6, lane = t & 63;
    if (lane == 0) { red[w] = s; red[4 + w] = s2; }
    __syncthreads();
    s  = red[0] + red[1] + red[2] + red[3];
    s2 = red[4] + red[5] + red[6] + red[7];
    const float mu  = s * (1.f / 1024.f);
    const float var = s2 * (1.f / 1024.f) - mu * mu;
    const float inv = rsqrtf(var + 1e-3f);
    ushort4 gv = *(const ushort4*)(gamma + t * 4);
    ushort4 bv = *(const ushort4*)(beta + t * 4);
    float o[4];
    o[0] = (v[0] - mu) * inv * bf2f(gv.x) + bf2f(bv.x);
    o[1] = (v[1] - mu) * inv * bf2f(gv.y) + bf2f(bv.y);
    o[2] = (v[2] - mu) * inv * bf2f(gv.z) + bf2f(bv.z);
    o[3] = (v[3] - mu) * inv * bf2f(gv.w) + bf2f(bv.w);
    if (fp32) {
        float4 fo = {o[0], o[1], o[2], o[3]};
        *(float4*)((float*)Out + row * 1024 + t * 4) = fo;
    } else {
        ushort4 bo;
        bo.x = f2bf(o[0]); bo.y = f2bf(o[1]); bo.z = f2bf(o[2]); bo.w = f2bf(o[3]);
        *(ushort4*)((u16*)Out + row * 1024 + t * 4) = bo;
    }
}

// ---------------------------------------------------------------- launch
extern "C" void kernel_launch(void* const* d_in, const int* in_sizes, int n_in,
                              void* d_out, int out_size, void* d_ws, size_t ws_size,
                              hipStream_t stream)
{
    (void)in_sizes; (void)n_in; (void)out_size; (void)ws_size;
    const void* X     = d_in[0];
    const void* Wq    = d_in[1];
    const void* bq    = d_in[2];
    const void* Wk    = d_in[3];
    const void* bk    = d_in[4];
    const void* Wv    = d_in[5];
    const void* bv    = d_in[6];
    const void* gamma = d_in[7];
    const void* beta  = d_in[8];

    char* ws = (char*)d_ws;
    u16* bias5 = (u16*)(ws + 16);
    u16* Wt    = (u16*)(ws + 16384);
    u16* QKV   = (u16*)(ws + 6307840);
    u16* Xb    = (u16*)(ws + 56639488);
    u16* S4    = (u16*)(ws + 73416704);
    u16* Vt4   = (u16*)(ws + 106971136);

    // 1. fused prologue
    prep_kernel<<<4869, 256, 0, stream>>>(
        X, Wq, Wk, Wv, bq, bk, bv, gamma, beta, Xb, Wt, bias5);

    // 2. QKV = Xb @ Wt^T + bias   (M=8192, N=3072, K=1024) -> 768 blocks, 3 rounds
    gemm256x128<0><<<dim3(24, 32, 1), 512, 0, stream>>>(
        Xb, 1024, 0, Wt, 1024, 0, QKV, 3072, 0, 1024, 1.f, bias5);

    // 3. S4[b] = (Q_b @ K_b^T)/32   (M=2048, N=2048, K=1024, z=4) -> 512, 2 rounds
    gemm256x128<1><<<dim3(16, 8, 4), 512, 0, stream>>>(
        QKV, 3072, (size_t)2048 * 3072,
        QKV + 1024, 3072, (size_t)2048 * 3072,
        S4, 2048, (size_t)2048 * 2048, 1024, 0.03125f, nullptr);

    // 4. softmax
    softmax_bf16_kernel<<<8192, 256, 0, stream>>>(S4);

    // 5. V^T
    transpose_v4_kernel<<<dim3(32, 16, 4), 256, 0, stream>>>(QKV, Vt4);

    // 6. Ctx_b = P_b @ V_b -> QKV Q slots  (M=2048, N=1024, K=2048, z=4) -> 256, 1 round
    gemm256x128<1><<<dim3(8, 8, 4), 512, 0, stream>>>(
        S4, 2048, (size_t)2048 * 2048,
        Vt4, 2048, (size_t)1024 * 2048,
        QKV, 3072, (size_t)2048 * 3072, 2048, 1.f, nullptr);

    // 7. LN
    resid_ln_kernel<<<8192, 256, 0, stream>>>(
        QKV, Xb, bias5 + 3 * 1024, bias5 + 4 * 1024, d_out, (const u16*)X);
}

// Round 4
// 280.215 us; speedup vs baseline: 1.0558x; 1.0558x over previous
//
#include <hip/hip_runtime.h>
#include <hip/hip_bf16.h>
#include <cstdint>
#include <cstddef>

// B=4, S=2048, D=1024. Inputs fp32 (runtime-detected, bf16 path kept).
// Round-11: best-engine-per-GEMM + V-transpose elimination.
//   proj (gemm128 r6 body, dual-mode, 1536 blocks = 6 exact CU-rounds):
//     blocks [0,1024):  QK2[8192][2048] = Xb @ Wt(q,k)^T + [bq|bk]  (col bias)
//     blocks [1024,1536): Vt[1024][8192] = Wv^T @ Xb^T + bv         (row bias)
//     -> V^T produced directly by GEMM; transpose_v4 kernel eliminated.
//   QK^T / PV: r9's gemm256r (256x256, ring-2, 1 barrier/iter) - measured
//     ~14 us faster combined than the 256x128 r10 engine.
//   PV split-K2 writes partial sums into the dead Q|K slots of QK2;
//   resid_ln sums both halves.
// Launches (6): prep, proj, gemm256r QK^T, softmax, gemm256r PV, resid_ln.
//
// d_ws layout (16B-aligned, ~107 MB):
//   bias5 @ 16           10,240   (bq|bk|bv|gamma|beta bf16)
//   Wt    @ 16,384       6,291,456   ([3][1024][1024]: q,k,v; [d_out][k])
//   QK2   @ 6,307,840    33,554,432  ([8192][2048]: Q|K, later Ctx0|Ctx1)
//   Xb    @ 39,862,272   16,777,216
//   S4/P4 @ 56,639,488   33,554,432
//   Vt    @ 90,193,920   16,777,216  ([1024][8192], batch b at col 2048b)

typedef unsigned short u16;
using bf16x8 = __attribute__((ext_vector_type(8))) short;
using f32x16 = __attribute__((ext_vector_type(16))) float;

typedef __attribute__((address_space(3))) unsigned int lds_uint;
typedef const __attribute__((address_space(1))) unsigned int glob_uint;

__device__ __forceinline__ float bf2f(u16 h) {
    union { unsigned int u; float f; } c;
    c.u = ((unsigned int)h) << 16;
    return c.f;
}
__device__ __forceinline__ u16 f2bf(float f) {
    union { float f; unsigned int u; } c;
    c.f = f;
    return (u16)((c.u + 0x7fffu + ((c.u >> 16) & 1u)) >> 16);  // RNE
}
__device__ __forceinline__ void load_lds16(const void* g, void* l) {
    __builtin_amdgcn_global_load_lds((glob_uint*)g, (lds_uint*)l, 16, 0, 0);
}

// Inline dtype detection: even-index u16s of X decode as bf16 to small finite
// nonzero values iff X is bf16; fp32 mantissa halves produce huge/NaN decodes.
__device__ __forceinline__ int detect_fp32(const u16* X, int* sflag) {
    const int t = threadIdx.x;
    if (t < 64) {
        bool bad = false, nz = false;
#pragma unroll
        for (int j = 0; j < 4; ++j) {
            float v = bf2f(X[(t * 4 + j) * 2]);
            if (!(fabsf(v) <= 1e9f)) bad = true;
            if (v != 0.f) nz = true;
        }
        unsigned long long ab = __ballot(bad);
        unsigned long long an = __ballot(nz);
        if (t == 0) *sflag = (ab != 0ull || an == 0ull) ? 1 : 0;
    }
    __syncthreads();
    return *sflag;
}

// ------------------------------------------------------------------- prep
__global__ __launch_bounds__(256) void prep_kernel(
    const void* __restrict__ X, const void* __restrict__ Wq,
    const void* __restrict__ Wk, const void* __restrict__ Wv,
    const void* __restrict__ bq, const void* __restrict__ bk,
    const void* __restrict__ bv, const void* __restrict__ gamma,
    const void* __restrict__ beta,
    u16* __restrict__ Xb, u16* __restrict__ Wt, u16* __restrict__ bias5)
{
    __shared__ u16 tile[64][72];
    __shared__ int sflag;
    const int fp32 = detect_fp32((const u16*)X, &sflag);
    const int t   = threadIdx.x;
    const int blk = blockIdx.x;

    if (blk < 4096) {                       // ---- convert X
        const size_t i = ((size_t)blk * 256 + t) * 8;
        if (fp32) {
            const float* f = (const float*)X;
            float4 a = *(const float4*)(f + i);
            float4 b = *(const float4*)(f + i + 4);
            ushort4 o0, o1;
            o0.x = f2bf(a.x); o0.y = f2bf(a.y); o0.z = f2bf(a.z); o0.w = f2bf(a.w);
            o1.x = f2bf(b.x); o1.y = f2bf(b.y); o1.z = f2bf(b.z); o1.w = f2bf(b.w);
            *(ushort4*)(Xb + i) = o0;
            *(ushort4*)(Xb + i + 4) = o1;
        } else {
            *(uint4*)(Xb + i) = *(const uint4*)((const u16*)X + i);
        }
    } else if (blk < 4864) {                // ---- transpose W
        const int idx = blk - 4096;
        const int k0 = (idx & 15) * 64;
        const int n0 = ((idx >> 4) & 15) * 64;
        const int w  = idx >> 8;
        const void* W = (w == 0) ? Wq : ((w == 1) ? Wk : Wv);
#pragma unroll
        for (int it = 0; it < 2; ++it) {
            int i2 = t + it * 256;
            int r = i2 >> 3;
            int c = (i2 & 7) * 8;
            const size_t off = (size_t)(k0 + r) * 1024 + n0 + c;
            if (fp32) {
                const float* Wf = (const float*)W + off;
                float4 a = *(const float4*)Wf;
                float4 b = *(const float4*)(Wf + 4);
                u16* tp = &tile[r][c];
                tp[0] = f2bf(a.x); tp[1] = f2bf(a.y); tp[2] = f2bf(a.z); tp[3] = f2bf(a.w);
                tp[4] = f2bf(b.x); tp[5] = f2bf(b.y); tp[6] = f2bf(b.z); tp[7] = f2bf(b.w);
            } else {
                *(uint4*)&tile[r][c] = *(const uint4*)((const u16*)W + off);
            }
        }
        __syncthreads();
#pragma unroll
        for (int it = 0; it < 2; ++it) {
            int i2 = t + it * 256;
            int r = i2 >> 3;
            int c = (i2 & 7) * 8;
            union { u16 s[8]; uint4 v; } tmp;
#pragma unroll
            for (int j = 0; j < 8; ++j) tmp.s[j] = tile[c + j][r];
            *(uint4*)(Wt + (size_t)(w * 1024 + n0 + r) * 1024 + k0 + c) = tmp.v;
        }
    } else {                                // ---- small vectors
        const int v = blk - 4864;
        const void* srcs[5] = {bq, bk, bv, gamma, beta};
        const void* src = srcs[v];
        u16* d = bias5 + (size_t)v * 1024;
        const int i = t * 4;
        if (fp32) {
            const float* f = (const float*)src;
            ushort4 o;
            o.x = f2bf(f[i]); o.y = f2bf(f[i + 1]);
            o.z = f2bf(f[i + 2]); o.w = f2bf(f[i + 3]);
            *(ushort4*)(d + i) = o;
        } else {
            *(ushort4*)(d + i) = *(const ushort4*)((const u16*)src + i);
        }
    }
}

// ------------------------------------------------- proj: QK gemm + V^T gemm
// Round-6 verified gemm128 body (128x128 tile, BK=64, 4 waves x 2x2 32x32x16,
// parity-independent XOR kgroup swizzle). 1536 one-dim blocks:
//   [0,1024):    QK2 = Xb @ Wt(qk)^T + bias[col]   (16 n-tiles x 64 m-tiles)
//   [1024,1536): Vt  = Wvt @ Xb^T   + bias[row]    (64 n-tiles x  8 m-tiles)
__global__ __launch_bounds__(256) void proj_kernel(
    const u16* __restrict__ Xb, const u16* __restrict__ Wt,
    u16* __restrict__ QK2, u16* __restrict__ Vt, const u16* __restrict__ bias5)
{
    __shared__ u16 As[2][128 * 32];
    __shared__ u16 Bs[2][128 * 32];
    const int id   = blockIdx.x;
    const bool vt  = (id >= 1024);
    const u16* A;  const u16* Bt;  u16* C;
    int lda, ldb, ldc, m0, n0;
    if (!vt) {
        A = Xb;  lda = 1024;  Bt = Wt;  ldb = 1024;  C = QK2;  ldc = 2048;
        n0 = (id & 15) * 128;  m0 = (id >> 4) * 128;
    } else {
        const int i2 = id - 1024;
        A = Wt + (size_t)2 * 1024 * 1024;  lda = 1024;   // Wv^T [d][k]
        Bt = Xb;  ldb = 1024;  C = Vt;  ldc = 8192;
        n0 = (i2 & 63) * 128;  m0 = (i2 >> 6) * 128;
    }
    const int t    = threadIdx.x;
    const int lane = t & 63;
    const int w    = t >> 6;
    const int wr   = w >> 1, wc = w & 1;

    // swizzled staging (wave w covers rows [w*32, w*32+32)); key = (srow>>1)&3
    const int srow = lane >> 2;
    const int skg  = (lane & 3) ^ ((srow >> 1) & 3);
    const u16* Ag0 = A  + (size_t)(m0 + w * 32 +      srow) * lda + skg * 8;
    const u16* Ag1 = A  + (size_t)(m0 + w * 32 + 16 + srow) * lda + skg * 8;
    const u16* Bg0 = Bt + (size_t)(n0 + w * 32 +      srow) * ldb + skg * 8;
    const u16* Bg1 = Bt + (size_t)(n0 + w * 32 + 16 + srow) * ldb + skg * 8;
    u16* Al0 = &As[0][(w * 32) * 32];
    u16* Al1 = &As[1][(w * 32) * 32];
    u16* Bl0 = &Bs[0][(w * 32) * 32];
    u16* Bl1 = &Bs[1][(w * 32) * 32];

    f32x16 acc[2][2];
#pragma unroll
    for (int mi = 0; mi < 2; ++mi)
#pragma unroll
        for (int ni = 0; ni < 2; ++ni)
#pragma unroll
            for (int r = 0; r < 16; ++r)
                acc[mi][ni][r] = 0.f;

    const int ml  = lane & 31;
    const int kh  = lane >> 5;
    const int key = (ml >> 1) & 3;

    for (int k0 = 0; k0 < 1024; k0 += 64) {
        load_lds16(Ag0 + k0,      Al0);
        load_lds16(Ag1 + k0,      Al0 + 16 * 32);
        load_lds16(Bg0 + k0,      Bl0);
        load_lds16(Bg1 + k0,      Bl0 + 16 * 32);
        load_lds16(Ag0 + k0 + 32, Al1);
        load_lds16(Ag1 + k0 + 32, Al1 + 16 * 32);
        load_lds16(Bg0 + k0 + 32, Bl1);
        load_lds16(Bg1 + k0 + 32, Bl1 + 16 * 32);
        __syncthreads();
#pragma unroll
        for (int slab = 0; slab < 2; ++slab) {
            const u16* as_ = As[slab];
            const u16* bs_ = Bs[slab];
#pragma unroll
            for (int s = 0; s < 2; ++s) {
                const int g    = s * 2 + kh;
                const int slot = (g ^ key) * 8;
                bf16x8 a0 = *(const bf16x8*)&as_[(wr * 64 +      ml) * 32 + slot];
                bf16x8 a1 = *(const bf16x8*)&as_[(wr * 64 + 32 + ml) * 32 + slot];
                bf16x8 b0 = *(const bf16x8*)&bs_[(wc * 64 +      ml) * 32 + slot];
                bf16x8 b1 = *(const bf16x8*)&bs_[(wc * 64 + 32 + ml) * 32 + slot];
                acc[0][0] = __builtin_amdgcn_mfma_f32_32x32x16_bf16(a0, b0, acc[0][0], 0, 0, 0);
                acc[0][1] = __builtin_amdgcn_mfma_f32_32x32x16_bf16(a0, b1, acc[0][1], 0, 0, 0);
                acc[1][0] = __builtin_amdgcn_mfma_f32_32x32x16_bf16(a1, b0, acc[1][0], 0, 0, 0);
                acc[1][1] = __builtin_amdgcn_mfma_f32_32x32x16_bf16(a1, b1, acc[1][1], 0, 0, 0);
            }
        }
        __syncthreads();
    }

    // C/D layout (m74/m101): col = lane&31, row = (r&3) + 8*(r>>2) + 4*(lane>>5)
    const int colb = n0 + wc * 64 + ml;
    const int rowb = m0 + wr * 64 + 4 * kh;
#pragma unroll
    for (int mi = 0; mi < 2; ++mi) {
#pragma unroll
        for (int ni = 0; ni < 2; ++ni) {
            const int col = colb + ni * 32;
            const float cbias = vt ? 0.f : bf2f(bias5[col]);
#pragma unroll
            for (int r = 0; r < 16; ++r) {
                const int row = rowb + mi * 32 + (r & 3) + 8 * (r >> 2);
                const float bias = vt ? bf2f(bias5[2048 + row]) : cbias;
                C[(size_t)row * ldc + col] = f2bf(acc[mi][ni][r] + bias);
            }
        }
    }
}

// --------------------------------------- GEMM 256x256, K64 ring-2, 1 barrier
// (round-9 verbatim - the measured best QK^T/PV engine; dup-stage guarded)
// LDS element map: LDS[buf][row][slot*8 + e] = G[row][64*slab + (slot^(row&7))*8 + e]
// C/D layout (m74/m101): col = lane&31, row = (r&3) + 8*(r>>2) + 4*(lane>>5).
template<int EPI, int KSPLIT>
__global__ __launch_bounds__(512, 2) void gemm256r(
    const u16* __restrict__ A, int lda, size_t sA,
    const u16* __restrict__ Bt, int ldb, size_t sB,
    u16* __restrict__ C, int ldc, size_t sC,
    int K, float scale, const u16* __restrict__ bias3)
{
    __shared__ u16 As[2][256 * 64];     // 64 KB
    __shared__ u16 Bs[2][256 * 64];     // 64 KB

    const int t  = threadIdx.x;
    const int l  = t & 63;
    const int w  = t >> 6;              // 0..7
    const int wm = w >> 2;              // 0..1
    const int wn = w & 3;               // 0..3
    const int m0 = blockIdx.y * 256;
    const int n0 = blockIdx.x * 256;
    const int batch = (int)blockIdx.z >> (KSPLIT - 1);
    const int ks    = (int)blockIdx.z & (KSPLIT - 1);
    A  += (size_t)batch * sA + (size_t)ks * K;
    Bt += (size_t)batch * sB + (size_t)ks * K;
    C  += (size_t)batch * sC + (size_t)ks * 1024;   // ks==0 when KSPLIT==1

    // ---- staging constants (pre-swizzled global source, linear LDS dest)
    const int srow = w * 8 + (l >> 3);              // row within 64-row round
    const int sg   = (l & 7) ^ (l >> 3);            // global k-group for this lane
    const u16* Ag = A  + (size_t)(m0 + srow) * lda + sg * 8;
    const u16* Bg = Bt + (size_t)(n0 + srow) * ldb + sg * 8;

    auto stage = [&](int j, int buf) {
        const size_t kb = (size_t)j * 64;
        const u16* ag = Ag + kb;
        const u16* bg = Bg + kb;
        u16* al = &As[buf][w * 512];
        u16* bl = &Bs[buf][w * 512];
#pragma unroll
        for (int i = 0; i < 4; ++i) {
            load_lds16(ag + (size_t)i * 64 * lda, al + i * 4096);
            load_lds16(bg + (size_t)i * 64 * ldb, bl + i * 4096);
        }
    };

    // ---- read-side constants
    const int lr   = l & 31;
    const int kh   = l >> 5;            // 0..1
    const int keyr = lr & 7;
    const int aoff = (wm * 128 + lr) * 64;
    const int boff = (wn * 64 + lr) * 64;

    f32x16 acc[4][2];
#pragma unroll
    for (int mi = 0; mi < 4; ++mi)
#pragma unroll
        for (int ni = 0; ni < 2; ++ni)
#pragma unroll
            for (int r = 0; r < 16; ++r) acc[mi][ni][r] = 0.f;

    const int NS = K >> 6;              // K64 slabs (>= 2 for all our shapes)

    // prologue: both buffers in flight, certify slab 0 (slab 1 stays in flight)
    stage(0, 0);
    stage(1, 1);
    asm volatile("s_waitcnt vmcnt(8)" ::: "memory");
    __builtin_amdgcn_s_barrier();
    asm volatile("" ::: "memory");

    for (int j = 0; j < NS; ++j) {
        const int buf = j & 1;
        const u16* as_ = &As[buf][aoff];
        const u16* bs_ = &Bs[buf][boff];
        bf16x8 a[4][4], b[2][4];
        // phase A reads (k 0..31)
#pragma unroll
        for (int ks2 = 0; ks2 < 2; ++ks2) {
            const int sp = ((ks2 * 2 + kh) ^ keyr) * 8;
#pragma unroll
            for (int mi = 0; mi < 4; ++mi) a[mi][ks2] = *(const bf16x8*)(as_ + mi * 2048 + sp);
#pragma unroll
            for (int ni = 0; ni < 2; ++ni) b[ni][ks2] = *(const bf16x8*)(bs_ + ni * 2048 + sp);
        }
        // prefetch next slab into the other buffer (its readers retired at the
        // previous iteration's end barrier); slab 1 already staged in prologue
        if (j + 1 < NS && j > 0) stage(j + 1, buf ^ 1);
        __builtin_amdgcn_s_setprio(1);
#pragma unroll
        for (int ks2 = 0; ks2 < 2; ++ks2)
#pragma unroll
            for (int mi = 0; mi < 4; ++mi)
#pragma unroll
                for (int ni = 0; ni < 2; ++ni)
                    acc[mi][ni] = __builtin_amdgcn_mfma_f32_32x32x16_bf16(
                        a[mi][ks2], b[ni][ks2], acc[mi][ni], 0, 0, 0);
        __builtin_amdgcn_s_setprio(0);
        // phase B reads (k 32..63)
#pragma unroll
        for (int ks2 = 2; ks2 < 4; ++ks2) {
            const int sp = ((ks2 * 2 + kh) ^ keyr) * 8;
#pragma unroll
            for (int mi = 0; mi < 4; ++mi) a[mi][ks2] = *(const bf16x8*)(as_ + mi * 2048 + sp);
#pragma unroll
            for (int ni = 0; ni < 2; ++ni) b[ni][ks2] = *(const bf16x8*)(bs_ + ni * 2048 + sp);
        }
        __builtin_amdgcn_s_setprio(1);
#pragma unroll
        for (int ks2 = 2; ks2 < 4; ++ks2)
#pragma unroll
            for (int mi = 0; mi < 4; ++mi)
#pragma unroll
                for (int ni = 0; ni < 2; ++ni)
                    acc[mi][ni] = __builtin_amdgcn_mfma_f32_32x32x16_bf16(
                        a[mi][ks2], b[ni][ks2], acc[mi][ni], 0, 0, 0);
        __builtin_amdgcn_s_setprio(0);
        if (j + 1 < NS) {
            // loads were issued a full MFMA block ago -> this wait is ~free
            asm volatile("s_waitcnt vmcnt(0)" ::: "memory");
            __builtin_amdgcn_s_barrier();
            asm volatile("" ::: "memory");
        }
    }

    // epilogue
    const int colb = n0 + wn * 64 + lr;
    const int rowb = m0 + wm * 128 + 4 * kh;
#pragma unroll
    for (int mi = 0; mi < 4; ++mi) {
#pragma unroll
        for (int ni = 0; ni < 2; ++ni) {
            const int col = colb + ni * 32;
            const float bias = (EPI == 0) ? bf2f(bias3[col]) : 0.f;
#pragma unroll
            for (int r = 0; r < 16; ++r) {
                const int row = rowb + mi * 32 + (r & 3) + 8 * (r >> 2);
                C[(size_t)row * ldc + col] = f2bf(acc[mi][ni][r] * scale + bias);
            }
        }
    }
}

// ----------------------------------------------------------- softmax (bf16)
__global__ __launch_bounds__(256) void softmax_bf16_kernel(u16* __restrict__ S)
{
    const int t = threadIdx.x;
    u16* sp = S + (size_t)blockIdx.x * 2048;
    union { uint4 v; u16 h[8]; } raw;
    raw.v = *(const uint4*)(sp + t * 8);
    float vals[8];
#pragma unroll
    for (int i = 0; i < 8; ++i) vals[i] = bf2f(raw.h[i]);
    float m = vals[0];
#pragma unroll
    for (int i = 1; i < 8; ++i) m = fmaxf(m, vals[i]);
#pragma unroll
    for (int off = 32; off > 0; off >>= 1) m = fmaxf(m, __shfl_xor(m, off));
    __shared__ float red[8];
    const int w = t >> 6, lane = t & 63;
    if (lane == 0) red[w] = m;
    __syncthreads();
    m = fmaxf(fmaxf(red[0], red[1]), fmaxf(red[2], red[3]));
    float e[8], s = 0.f;
#pragma unroll
    for (int i = 0; i < 8; ++i) { e[i] = __expf(vals[i] - m); s += e[i]; }
#pragma unroll
    for (int off = 32; off > 0; off >>= 1) s += __shfl_xor(s, off);
    if (lane == 0) red[4 + w] = s;
    __syncthreads();
    s = red[4] + red[5] + red[6] + red[7];
    const float rinv = 1.f / s;
    union { uint4 v; u16 h[8]; } out;
#pragma unroll
    for (int i = 0; i < 8; ++i) out.h[i] = f2bf(e[i] * rinv);
    *(uint4*)(sp + t * 8) = out.v;
}

// ---------------------------------------------------------------- resid + LN
// Ctx is split across the Q-slot (cols 0..1023) and K-slot (cols 1024..2047)
// of QK2 (PV split-K2 partial sums); sum both halves here.
__global__ __launch_bounds__(256) void resid_ln_kernel(
    const u16* __restrict__ Ctx, const u16* __restrict__ Xb,
    const u16* __restrict__ gamma, const u16* __restrict__ beta,
    void* __restrict__ Out, const u16* __restrict__ Xraw)
{
    __shared__ int sflag;
    const int fp32 = detect_fp32(Xraw, &sflag);
    const size_t row = blockIdx.x;
    const int t = threadIdx.x;
    ushort4 cv0 = *(const ushort4*)(Ctx + row * 2048 + t * 4);
    ushort4 cv1 = *(const ushort4*)(Ctx + row * 2048 + 1024 + t * 4);
    ushort4 xv  = *(const ushort4*)(Xb + row * 1024 + t * 4);
    float v[4] = {bf2f(cv0.x) + bf2f(cv1.x) + bf2f(xv.x),
                  bf2f(cv0.y) + bf2f(cv1.y) + bf2f(xv.y),
                  bf2f(cv0.z) + bf2f(cv1.z) + bf2f(xv.z),
                  bf2f(cv0.w) + bf2f(cv1.w) + bf2f(xv.w)};
    float s  = v[0] + v[1] + v[2] + v[3];
    float s2 = v[0] * v[0] + v[1] * v[1] + v[2] * v[2] + v[3] * v[3];
#pragma unroll
    for (int off = 32; off > 0; off >>= 1) {
        s  += __shfl_xor(s, off);
        s2 += __shfl_xor(s2, off);
    }
    __shared__ float red[8];
    const int w = t >> 6, lane = t & 63;
    if (lane == 0) { red[w] = s; red[4 + w] = s2; }
    __syncthreads();
    s  = red[0] + red[1] + red[2] + red[3];
    s2 = red[4] + red[5] + red[6] + red[7];
    const float mu  = s * (1.f / 1024.f);
    const float var = s2 * (1.f / 1024.f) - mu * mu;
    const float inv = rsqrtf(var + 1e-3f);
    ushort4 gv = *(const ushort4*)(gamma + t * 4);
    ushort4 bv = *(const ushort4*)(beta + t * 4);
    float o[4];
    o[0] = (v[0] - mu) * inv * bf2f(gv.x) + bf2f(bv.x);
    o[1] = (v[1] - mu) * inv * bf2f(gv.y) + bf2f(bv.y);
    o[2] = (v[2] - mu) * inv * bf2f(gv.z) + bf2f(bv.z);
    o[3] = (v[3] - mu) * inv * bf2f(gv.w) + bf2f(bv.w);
    if (fp32) {
        float4 fo = {o[0], o[1], o[2], o[3]};
        *(float4*)((float*)Out + row * 1024 + t * 4) = fo;
    } else {
        ushort4 bo;
        bo.x = f2bf(o[0]); bo.y = f2bf(o[1]); bo.z = f2bf(o[2]); bo.w = f2bf(o[3]);
        *(ushort4*)((u16*)Out + row * 1024 + t * 4) = bo;
    }
}

// ---------------------------------------------------------------- launch
extern "C" void kernel_launch(void* const* d_in, const int* in_sizes, int n_in,
                              void* d_out, int out_size, void* d_ws, size_t ws_size,
                              hipStream_t stream)
{
    (void)in_sizes; (void)n_in; (void)out_size; (void)ws_size;
    const void* X     = d_in[0];
    const void* Wq    = d_in[1];
    const void* bq    = d_in[2];
    const void* Wk    = d_in[3];
    const void* bk    = d_in[4];
    const void* Wv    = d_in[5];
    const void* bv    = d_in[6];
    const void* gamma = d_in[7];
    const void* beta  = d_in[8];

    char* ws = (char*)d_ws;
    u16* bias5 = (u16*)(ws + 16);
    u16* Wt    = (u16*)(ws + 16384);
    u16* QK2   = (u16*)(ws + 6307840);
    u16* Xb    = (u16*)(ws + 39862272);
    u16* S4    = (u16*)(ws + 56639488);
    u16* Vt    = (u16*)(ws + 90193920);

    // 1. fused prologue
    prep_kernel<<<4869, 256, 0, stream>>>(
        X, Wq, Wk, Wv, bq, bk, bv, gamma, beta, Xb, Wt, bias5);

    // 2. proj: QK2 = Xb @ Wt(qk)^T + [bq|bk]  (1024 blocks)
    //          Vt  = Wv^T @ Xb^T + bv          (512 blocks)  -> 6 exact rounds
    proj_kernel<<<1536, 256, 0, stream>>>(Xb, Wt, QK2, Vt, bias5);

    // 3. S4[b] = (Q_b @ K_b^T)/32   (M=N=2048, K=1024, z=4) -> 256 blocks
    gemm256r<1, 1><<<dim3(8, 8, 4), 512, 0, stream>>>(
        QK2, 2048, (size_t)2048 * 2048,
        QK2 + 1024, 2048, (size_t)2048 * 2048,
        S4, 2048, (size_t)2048 * 2048, 1024, 0.03125f, nullptr);

    // 4. softmax
    softmax_bf16_kernel<<<8192, 256, 0, stream>>>(S4);

    // 5. Ctx_b = P_b @ V_b, split-K2 -> Q-slot (ks=0) + K-slot (ks=1) of QK2
    //    (M=2048, N=1024, K=1024 per half, z = 4 x 2) -> 256 blocks
    gemm256r<1, 2><<<dim3(4, 8, 8), 512, 0, stream>>>(
        S4, 2048, (size_t)2048 * 2048,
        Vt, 8192, (size_t)2048,
        QK2, 2048, (size_t)2048 * 2048, 1024, 1.f, nullptr);

    // 6. LN (sums the two Ctx halves)
    resid_ln_kernel<<<8192, 256, 0, stream>>>(
        QK2, Xb, bias5 + 3 * 1024, bias5 + 4 * 1024, d_out, (const u16*)X);
}